// Round 5
// baseline (269.222 us; speedup 1.0000x reference)
//
#include <hip/hip_runtime.h>
#include <math.h>

// SpatialSampler: B=256, A=64, k=64, P=32, BETA=0.1
// out = [places (33.55M f32) | sampled_points (33.55M f32)] = 268.4 MB
//   places[bp,j,k]  = h[bp,j] * v[bp,k]
//   sampled[bp,j,k] = 100*h[jmax]*v[kmax] at (jmax,kmax), else 0
//
// Round 5: merged roles. 2048 blocks x 256 threads = 8192 waves; wave w
// owns BOTH tiles of bp = w (places + sampled, 32 KB total, 32 dwordx4
// stores/thread). The serial argmax chain (2x logf + 24-shuffle, ~700 cy)
// now issues UNDER the wave's own 16 in-flight places stores instead of
// stalling a dedicated sampled-role wave with nothing else to do.
// x_cat/noise row read once per bp (was twice). Full single-round
// residency: 8 blocks/CU x 4 waves = 32 waves/CU.

#define BETA 0.1f
#define PLACES_ELEMS 33554432ull     // 256*32*64*64

typedef float vfloat4 __attribute__((ext_vector_type(4)));

__global__ __launch_bounds__(256) void fused_sampler(
    const float* __restrict__ x_cat,
    const float* __restrict__ noise,
    float* __restrict__ out)
{
    const int w    = blockIdx.x * 4 + (threadIdx.x >> 6);  // wave id = bp
    const int lane = threadIdx.x & 63;
    const int c    = lane & 15;           // col quad 0..15
    const int j0   = lane >> 4;           // row phase 0..3

    const float* __restrict__ xrow = x_cat + (size_t)w * 128;
    const float* __restrict__ nrow = noise + (size_t)w * 128;

    // ---- all loads up front (independent, L1/L2-resident) ----
    const float h  = xrow[lane];          // h[lane] (argmax input)
    const float v  = xrow[64 + lane];     // v[lane] (argmax input)
    const float nh = nrow[lane];
    const float nv = nrow[64 + lane];
    const vfloat4 v4 = *(const vfloat4*)(xrow + 64 + 4 * c);  // places B
    float hb[16];                         // places A broadcasts
    #pragma unroll
    for (int r = 0; r < 16; ++r) hb[r] = xrow[j0 + 4 * r];

    // logf early so the transcendental latency hides under the stores too
    float lph = logf(h) + BETA * nh;
    float lpv = logf(v) + BETA * nv;

    // ---- places tile: 16 independent 1KB-contiguous dwordx4 stores ----
    vfloat4* __restrict__ pout = (vfloat4*)out + (size_t)w * 1024;
    #pragma unroll
    for (int r = 0; r < 16; ++r)
        pout[lane + 64 * r] = hb[r] * v4;

    // ---- argmax chain: issues while the places stores drain ----
    int jh = lane, jv = lane;
    #pragma unroll
    for (int off = 32; off > 0; off >>= 1) {
        const float oh = __shfl_xor(lph, off, 64);
        const int   oi = __shfl_xor(jh,  off, 64);
        const float ov = __shfl_xor(lpv, off, 64);
        const int   oj = __shfl_xor(jv,  off, 64);
        if (oh > lph || (oh == lph && oi < jh)) { lph = oh; jh = oi; }
        if (ov > lpv || (ov == lpv && oj < jv)) { lpv = ov; jv = oj; }
    }
    // jh/jv wave-uniform argmax (smallest index on exact ties)
    const float sval = 100.0f * __shfl(h, jh, 64) * __shfl(v, jv, 64);

    // ---- sampled tile: near-all-zero stores, single merged nonzero ----
    vfloat4* __restrict__ sout =
        (vfloat4*)(out + PLACES_ELEMS) + (size_t)w * 1024;
    const int kjv = jv >> 2;              // f4-column holding vmax
    const int mjv = jv & 3;               // element within that f4

    #pragma unroll
    for (int r = 0; r < 16; ++r) {
        const int j = j0 + 4 * r;         // row of this store (addr lane+64r)
        const bool hit = (j == jh) & (c == kjv);
        // compile-time component writes only (runtime index -> scratch)
        vfloat4 sv;
        sv.x = (hit && mjv == 0) ? sval : 0.f;
        sv.y = (hit && mjv == 1) ? sval : 0.f;
        sv.z = (hit && mjv == 2) ? sval : 0.f;
        sv.w = (hit && mjv == 3) ? sval : 0.f;
        sout[lane + 64 * r] = sv;
    }
}

extern "C" void kernel_launch(void* const* d_in, const int* in_sizes, int n_in,
                              void* d_out, int out_size, void* d_ws, size_t ws_size,
                              hipStream_t stream) {
    const float* x_cat = (const float*)d_in[0];
    const float* noise = (const float*)d_in[1];
    float* out = (float*)d_out;

    // 2048 blocks x 256 threads = 8192 waves; wave w -> both tiles of bp=w.
    // 32 dwordx4 stores per thread = full 268.4 MB output, one dispatch.
    fused_sampler<<<dim3(2048), dim3(256), 0, stream>>>(x_cat, noise, out);
}

// Round 6
// 266.478 us; speedup vs baseline: 1.0103x; 1.0103x over previous
//
#include <hip/hip_runtime.h>
#include <math.h>

// SpatialSampler: B=256, A=64, k=64, P=32, BETA=0.1
// out = [places (33.55M f32) | sampled_points (33.55M f32)] = 268.4 MB
//   places[bp,j,k]  = h[bp,j] * v[bp,k]
//   sampled[bp,j,k] = 100*h[jmax]*v[kmax] at (jmax,kmax), else 0
//
// Round 6: revert to round-4 role-split (best measured: 262.9 on a
// throttled chip) + cheaper argmax on the sampled-role waves.
//   2048 blocks x 256 threads = 8192 waves, one residency round
//   (8 blocks/CU x 4 waves = 32 waves/CU).
//   waves [0,4096):    places tiles bp = 2w, 2w+1 (32 KB contiguous,
//                      32 dwordx4 stores/thread; unchanged from r4)
//   waves [4096,8192): sampled tiles bp = 2(w-4096)+{0,1}.
//     Argmax = max-reduce (6 fmax-shuffle steps/channel) + ballot+ffs
//     for the index: half the VALU work of the index-carrying butterfly,
//     and all FOUR chains (h/v x 2 tiles) run interleaved for ILP
//     before the 32-store contiguous run. Smallest-index ties preserved.

#define BETA 0.1f
#define PLACES_ELEMS 33554432ull     // 256*32*64*64

typedef float vfloat4 __attribute__((ext_vector_type(4)));

__global__ __launch_bounds__(256) void fused_sampler(
    const float* __restrict__ x_cat,
    const float* __restrict__ noise,
    float* __restrict__ out)
{
    const int w    = blockIdx.x * 4 + (threadIdx.x >> 6);  // wave id [0,8192)
    const int lane = threadIdx.x & 63;
    const int c    = lane & 15;           // col quad 0..15
    const int j0   = lane >> 4;           // row phase 0..3

    if (w < 4096) {
        // ---------------- places: 2 tiles, 32 KB contiguous ----------------
        #pragma unroll
        for (int q = 0; q < 2; ++q) {
            const int bp = 2 * w + q;
            const float* __restrict__ xrow = x_cat + (size_t)bp * 128;
            vfloat4* __restrict__ pout = (vfloat4*)out + (size_t)bp * 1024;

            const vfloat4 v4 = *(const vfloat4*)(xrow + 64 + 4 * c);
            float h[16];
            #pragma unroll
            for (int r = 0; r < 16; ++r) h[r] = xrow[j0 + 4 * r];

            // 16 independent stores; addr = lane + 64*r: each wave
            // instruction covers a contiguous aligned 1 KB.
            #pragma unroll
            for (int r = 0; r < 16; ++r)
                pout[lane + 64 * r] = h[r] * v4;
        }
    } else {
        // -------- sampled: both argmaxes first (ILP), then 32 stores -------
        const int bp0 = 2 * (w - 4096);
        const float* __restrict__ xrow0 = x_cat + (size_t)bp0 * 128;
        const float* __restrict__ nrow0 = noise + (size_t)bp0 * 128;
        const float* __restrict__ xrow1 = xrow0 + 128;
        const float* __restrict__ nrow1 = nrow0 + 128;

        const float h0 = xrow0[lane], v0 = xrow0[64 + lane];
        const float h1 = xrow1[lane], v1 = xrow1[64 + lane];
        const float a0 = logf(h0) + BETA * nrow0[lane];
        const float b0 = logf(v0) + BETA * nrow0[64 + lane];
        const float a1 = logf(h1) + BETA * nrow1[lane];
        const float b1 = logf(v1) + BETA * nrow1[64 + lane];

        // four independent max-reduce chains, interleaved
        float ma0 = a0, mb0 = b0, ma1 = a1, mb1 = b1;
        #pragma unroll
        for (int off = 32; off > 0; off >>= 1) {
            ma0 = fmaxf(ma0, __shfl_xor(ma0, off, 64));
            mb0 = fmaxf(mb0, __shfl_xor(mb0, off, 64));
            ma1 = fmaxf(ma1, __shfl_xor(ma1, off, 64));
            mb1 = fmaxf(mb1, __shfl_xor(mb1, off, 64));
        }
        // smallest lane achieving the max == reference argmax tie-break
        const int jh0 = __ffsll((unsigned long long)__ballot(a0 == ma0)) - 1;
        const int jv0 = __ffsll((unsigned long long)__ballot(b0 == mb0)) - 1;
        const int jh1 = __ffsll((unsigned long long)__ballot(a1 == ma1)) - 1;
        const int jv1 = __ffsll((unsigned long long)__ballot(b1 == mb1)) - 1;

        const float sval0 = 100.0f * __shfl(h0, jh0, 64) * __shfl(v0, jv0, 64);
        const float sval1 = 100.0f * __shfl(h1, jh1, 64) * __shfl(v1, jv1, 64);

        vfloat4* __restrict__ sout =
            (vfloat4*)(out + PLACES_ELEMS) + (size_t)bp0 * 1024;

        #pragma unroll
        for (int q = 0; q < 2; ++q) {
            const int   jh   = q ? jh1 : jh0;
            const int   jv   = q ? jv1 : jv0;
            const float sval = q ? sval1 : sval0;
            const int   kjv  = jv >> 2;   // f4-column holding vmax
            const int   mjv  = jv & 3;    // element within that f4
            vfloat4* __restrict__ so = sout + q * 1024;

            #pragma unroll
            for (int r = 0; r < 16; ++r) {
                const int j = j0 + 4 * r; // row of this store (addr lane+64r)
                const bool hit = (j == jh) & (c == kjv);
                // compile-time component writes only (runtime index->scratch)
                vfloat4 sv;
                sv.x = (hit && mjv == 0) ? sval : 0.f;
                sv.y = (hit && mjv == 1) ? sval : 0.f;
                sv.z = (hit && mjv == 2) ? sval : 0.f;
                sv.w = (hit && mjv == 3) ? sval : 0.f;
                so[lane + 64 * r] = sv;
            }
        }
    }
}

extern "C" void kernel_launch(void* const* d_in, const int* in_sizes, int n_in,
                              void* d_out, int out_size, void* d_ws, size_t ws_size,
                              hipStream_t stream) {
    const float* x_cat = (const float*)d_in[0];
    const float* noise = (const float*)d_in[1];
    float* out = (float*)d_out;

    // 2048 blocks x 256 threads = 8192 waves; role-split, 2 tiles/wave.
    // 32 dwordx4 stores per thread = full 268.4 MB output, one dispatch.
    fused_sampler<<<dim3(2048), dim3(256), 0, stream>>>(x_cat, noise, out);
}